// Round 3
// baseline (390.942 us; speedup 1.0000x reference)
//
#include <hip/hip_runtime.h>
#include <hip/hip_bf16.h>
#include <math.h>

#define Bc 2
#define Lc 1024
#define Dc 768
#define Hc 12
#define DHc 64
#define BLD (Bc * Lc * Dc)   // 1,572,864
#define Mrows (Bc * Lc)      // 2048
#define CS 64
#define NC (Lc / CS)         // 16
#define STATE (DHc * DHc + DHc)  // 4160

using f32x4  = __attribute__((ext_vector_type(4))) float;
using bf16x8 = __attribute__((ext_vector_type(8))) short;
using bf16x4 = __attribute__((ext_vector_type(4))) short;

__device__ inline short f2bf(float x) {  // RNE fp32 -> bf16 bits
    unsigned u = __builtin_bit_cast(unsigned, x);
    u = (u + 0x7FFFu + ((u >> 16) & 1u)) >> 16;
    return (short)u;
}
__device__ inline float bf2f(short s) {
    unsigned u = ((unsigned)(unsigned short)s) << 16;
    return __builtin_bit_cast(float, u);
}

// ---------------------------------------------------------------------------
// LayerNorm (unchanged from round 2 — was fine)
// ---------------------------------------------------------------------------
__global__ __launch_bounds__(256) void ln_kernel(const float* __restrict__ x,
                                                 const float* __restrict__ g,
                                                 const float* __restrict__ b,
                                                 float* __restrict__ xn) {
    const int row = blockIdx.x;
    const float* xr = x + (size_t)row * Dc;
    float v[3];
    float s = 0.f, ss = 0.f;
#pragma unroll
    for (int i = 0; i < 3; ++i) {
        v[i] = xr[threadIdx.x + i * 256];
        s += v[i];
        ss += v[i] * v[i];
    }
#pragma unroll
    for (int off = 32; off > 0; off >>= 1) {
        s  += __shfl_down(s, off, 64);
        ss += __shfl_down(ss, off, 64);
    }
    __shared__ float sw[2][4];
    const int wave = threadIdx.x >> 6;
    const int lane = threadIdx.x & 63;
    if (lane == 0) { sw[0][wave] = s; sw[1][wave] = ss; }
    __syncthreads();
    s  = sw[0][0] + sw[0][1] + sw[0][2] + sw[0][3];
    ss = sw[1][0] + sw[1][1] + sw[1][2] + sw[1][3];
    const float mu = s * (1.f / Dc);
    const float var = ss * (1.f / Dc) - mu * mu;
    const float rstd = rsqrtf(var + 1e-5f);
    float* xo = xn + (size_t)row * Dc;
#pragma unroll
    for (int i = 0; i < 3; ++i) {
        const int c = threadIdx.x + i * 256;
        xo[c] = (v[i] - mu) * rstd * g[c] + b[c];
    }
}

// ---------------------------------------------------------------------------
// Weight transpose: W (K x N) -> Wt (N x K), 32x32 LDS tiles
// ---------------------------------------------------------------------------
__global__ __launch_bounds__(256) void transpose_kernel(const float* __restrict__ W,
                                                        float* __restrict__ Wt,
                                                        int K, int N) {
    __shared__ float t[32][33];
    const int bx = blockIdx.x * 32;  // n
    const int by = blockIdx.y * 32;  // k
    const int tx = threadIdx.x & 31, ty = threadIdx.x >> 5;  // ty 0..7
#pragma unroll
    for (int j = 0; j < 4; ++j)
        t[ty + 8 * j][tx] = W[(size_t)(by + ty + 8 * j) * N + bx + tx];
    __syncthreads();
#pragma unroll
    for (int j = 0; j < 4; ++j)
        Wt[(size_t)(bx + ty + 8 * j) * K + by + tx] = t[tx][ty + 8 * j];
}

// ---------------------------------------------------------------------------
// bf16x2-split MFMA GEMM: C[M,N] = A[M,K] @ Bt[N,K]^T + bias
// EPI: 0 none, 1 sigmoid, 2 qkv featurize. NP: 1 = plain bf16, 3 = bf16x2.
// 128x128 tile, 256 thr (4 waves, 2x2), BK=32, 16x16x32 bf16 MFMA.
// LDS rows padded to 40 shorts (80 B): start-bank stride 20 -> 2-way (free).
// ---------------------------------------------------------------------------
template <int EPI, int NP>
__global__ __launch_bounds__(256) void gemm_mfma(const float* __restrict__ A,
                                                 const float* __restrict__ Bt,
                                                 const float* __restrict__ bias,
                                                 const float* __restrict__ gate,
                                                 float* __restrict__ C,
                                                 int M, int N, int K) {
    __shared__ short Ah[128][40];
    __shared__ short Bh[128][40];
    __shared__ short Al[128][40];
    __shared__ short Bl[128][40];
    const int tid  = threadIdx.x;
    const int lane = tid & 63;
    const int wave = tid >> 6;
    const int wr = (wave >> 1) * 64;
    const int wc = (wave & 1) * 64;
    const int l15 = lane & 15;
    const int l4  = lane >> 4;
    const int row0 = blockIdx.y * 128;
    const int col0 = blockIdx.x * 128;

    f32x4 acc[4][4];
    const f32x4 zero = {0.f, 0.f, 0.f, 0.f};
#pragma unroll
    for (int i = 0; i < 4; ++i)
#pragma unroll
        for (int j = 0; j < 4; ++j) acc[i][j] = zero;

    for (int k0 = 0; k0 < K; k0 += 32) {
#pragma unroll
        for (int j = 0; j < 4; ++j) {
            const int i  = tid + j * 256;       // 0..1023
            const int r  = i >> 3;              // 0..127
            const int c4 = (i & 7) * 4;         // 0..28
            const float4 av = *reinterpret_cast<const float4*>(
                &A[(size_t)(row0 + r) * K + k0 + c4]);
            const float4 bv = *reinterpret_cast<const float4*>(
                &Bt[(size_t)(col0 + r) * K + k0 + c4]);
            const float aa[4] = {av.x, av.y, av.z, av.w};
            const float bb[4] = {bv.x, bv.y, bv.z, bv.w};
            bf16x4 ah, bh, al, bl;
#pragma unroll
            for (int e = 0; e < 4; ++e) {
                const short h = f2bf(aa[e]); ah[e] = h;
                const short g = f2bf(bb[e]); bh[e] = g;
                if (NP > 1) {
                    al[e] = f2bf(aa[e] - bf2f(h));
                    bl[e] = f2bf(bb[e] - bf2f(g));
                }
            }
            *reinterpret_cast<bf16x4*>(&Ah[r][c4]) = ah;
            *reinterpret_cast<bf16x4*>(&Bh[r][c4]) = bh;
            if (NP > 1) {
                *reinterpret_cast<bf16x4*>(&Al[r][c4]) = al;
                *reinterpret_cast<bf16x4*>(&Bl[r][c4]) = bl;
            }
        }
        __syncthreads();
        bf16x8 af[4], bfr[4], afl[4], bfl[4];
#pragma unroll
        for (int f = 0; f < 4; ++f) {
            af[f]  = *reinterpret_cast<bf16x8*>(&Ah[wr + f * 16 + l15][l4 * 8]);
            bfr[f] = *reinterpret_cast<bf16x8*>(&Bh[wc + f * 16 + l15][l4 * 8]);
            if (NP > 1) {
                afl[f] = *reinterpret_cast<bf16x8*>(&Al[wr + f * 16 + l15][l4 * 8]);
                bfl[f] = *reinterpret_cast<bf16x8*>(&Bl[wc + f * 16 + l15][l4 * 8]);
            }
        }
#pragma unroll
        for (int fi = 0; fi < 4; ++fi)
#pragma unroll
            for (int fj = 0; fj < 4; ++fj) {
                acc[fi][fj] = __builtin_amdgcn_mfma_f32_16x16x32_bf16(
                    af[fi], bfr[fj], acc[fi][fj], 0, 0, 0);
                if (NP > 1) {
                    acc[fi][fj] = __builtin_amdgcn_mfma_f32_16x16x32_bf16(
                        afl[fi], bfr[fj], acc[fi][fj], 0, 0, 0);
                    acc[fi][fj] = __builtin_amdgcn_mfma_f32_16x16x32_bf16(
                        af[fi], bfl[fj], acc[fi][fj], 0, 0, 0);
                }
            }
        __syncthreads();
    }
    // epilogue: C/D mapping (m89-verified): col=lane&15, row=(lane>>4)*4+reg
#pragma unroll
    for (int fi = 0; fi < 4; ++fi) {
#pragma unroll
        for (int fj = 0; fj < 4; ++fj) {
            const int col  = col0 + wc + fj * 16 + l15;
            const int rowb = row0 + wr + fi * 16 + l4 * 4;
            const float bv = bias[col];
#pragma unroll
            for (int j = 0; j < 4; ++j) {
                float v = acc[fi][fj][j] + bv;
                const int r = rowb + j;
                if (EPI == 1) v = 1.f / (1.f + expf(-v));
                if (EPI == 2) {
                    if (col < 2 * Dc) {  // q or k -> elu(.)+1 (k pre-scaled by gate)
                        float t = v;
                        if (col >= Dc) t *= gate[(size_t)r * Dc + (col - Dc)];
                        v = t > 0.f ? t + 1.f : expf(t);
                    }
                }
                C[(size_t)r * N + col] = v;
            }
        }
    }
}

// ---------------------------------------------------------------------------
// Phase A: chunk-local sum k_f (x) v and sum k_f. 1 wave per (chunk, b*h).
// Lane e owns state column e; k broadcast from LDS; zero in-loop barriers.
// ---------------------------------------------------------------------------
__global__ __launch_bounds__(64) void chunk_sum2(const float* __restrict__ qkv,
                                                 float* __restrict__ cbuf) {
    const int c = blockIdx.x, bh = blockIdx.y;
    const int b = bh / Hc, h = bh % Hc;
    const int lane = threadIdx.x;
    __shared__ float ks[CS][DHc];
    const size_t row0  = (size_t)b * Lc + c * CS;
    const size_t qbase = row0 * (3 * Dc) + h * DHc;
    for (int l = 0; l < CS; ++l)
        ks[l][lane] = qkv[qbase + (size_t)l * 3 * Dc + Dc + lane];
    __syncthreads();
    float S[DHc];
#pragma unroll
    for (int d = 0; d < DHc; ++d) S[d] = 0.f;
    float ksum = 0.f;
    for (int l = 0; l < CS; ++l) {
        const float vv = qkv[qbase + (size_t)l * 3 * Dc + 2 * Dc + lane];
        ksum += ks[l][lane];
#pragma unroll
        for (int d4 = 0; d4 < DHc / 4; ++d4) {
            const float4 k4 = *reinterpret_cast<const float4*>(&ks[l][d4 * 4]);
            S[d4 * 4 + 0] = fmaf(k4.x, vv, S[d4 * 4 + 0]);
            S[d4 * 4 + 1] = fmaf(k4.y, vv, S[d4 * 4 + 1]);
            S[d4 * 4 + 2] = fmaf(k4.z, vv, S[d4 * 4 + 2]);
            S[d4 * 4 + 3] = fmaf(k4.w, vv, S[d4 * 4 + 3]);
        }
    }
    float* out = cbuf + ((size_t)bh * NC + c) * STATE;
#pragma unroll
    for (int d = 0; d < DHc; ++d) out[d * DHc + lane] = S[d];
    out[DHc * DHc + lane] = ksum;
}

// ---------------------------------------------------------------------------
// Phase B: exclusive prefix scan over NC chunk states, 256-wide slabs
// ---------------------------------------------------------------------------
__global__ __launch_bounds__(256) void scan_kernel(float* __restrict__ cbuf) {
    const int idx = blockIdx.x * 256 + threadIdx.x;
    if (idx >= STATE) return;
    float* base = cbuf + (size_t)blockIdx.y * NC * STATE + idx;
    float r = 0.f;
    for (int c = 0; c < NC; ++c) {
        const float cur = base[(size_t)c * STATE];
        base[(size_t)c * STATE] = r;
        r += cur;
    }
}

// ---------------------------------------------------------------------------
// Phase C: 64-step recurrence per (chunk, b*h), 1 wave, state in registers,
// zero in-loop barriers. Lane e owns S[:, e]; kc replicated per lane.
// ---------------------------------------------------------------------------
__global__ __launch_bounds__(64) void chunk_out2(const float* __restrict__ qkv,
                                                 const float* __restrict__ cbuf,
                                                 float* __restrict__ attn) {
    const int c = blockIdx.x, bh = blockIdx.y;
    const int b = bh / Hc, h = bh % Hc;
    const int lane = threadIdx.x;
    __shared__ float kq[CS][DHc][2];  // [l][d][{k,q}]
    const size_t row0  = (size_t)b * Lc + c * CS;
    const size_t qbase = row0 * (3 * Dc) + h * DHc;
    for (int l = 0; l < CS; ++l) {
        kq[l][lane][0] = qkv[qbase + (size_t)l * 3 * Dc + Dc + lane];
        kq[l][lane][1] = qkv[qbase + (size_t)l * 3 * Dc + lane];
    }
    const float* P = cbuf + ((size_t)bh * NC + c) * STATE;
    float S[DHc], kc[DHc];
#pragma unroll
    for (int d = 0; d < DHc; ++d) S[d] = P[d * DHc + lane];
#pragma unroll
    for (int d = 0; d < DHc; ++d) kc[d] = P[DHc * DHc + d];
    __syncthreads();
    for (int l = 0; l < CS; ++l) {
        const float vv = qkv[qbase + (size_t)l * 3 * Dc + 2 * Dc + lane];
        float num = 0.f, den = 0.f;
#pragma unroll
        for (int d2 = 0; d2 < DHc / 2; ++d2) {
            const float4 t = *reinterpret_cast<const float4*>(&kq[l][d2 * 2][0]);
            S[2 * d2]      = fmaf(t.x, vv, S[2 * d2]);
            kc[2 * d2]    += t.x;
            num = fmaf(t.y, S[2 * d2], num);
            den = fmaf(t.y, kc[2 * d2], den);
            S[2 * d2 + 1]   = fmaf(t.z, vv, S[2 * d2 + 1]);
            kc[2 * d2 + 1] += t.z;
            num = fmaf(t.w, S[2 * d2 + 1], num);
            den = fmaf(t.w, kc[2 * d2 + 1], den);
        }
        attn[(row0 + l) * Dc + h * DHc + lane] = num / (den + 1e-6f);
    }
}

// ---------------------------------------------------------------------------
extern "C" void kernel_launch(void* const* d_in, const int* in_sizes, int n_in,
                              void* d_out, int out_size, void* d_ws, size_t ws_size,
                              hipStream_t stream) {
    const float* x      = (const float*)d_in[0];
    const float* W_qkv  = (const float*)d_in[1];
    const float* b_qkv  = (const float*)d_in[2];
    const float* W_gate = (const float*)d_in[3];
    const float* b_gate = (const float*)d_in[4];
    const float* W_proj = (const float*)d_in[5];
    const float* b_proj = (const float*)d_in[6];
    const float* ln_g   = (const float*)d_in[7];
    const float* ln_b   = (const float*)d_in[8];

    float* out_proj = (float*)d_out;           // (B,L,D)
    float* out_gate = out_proj + (size_t)BLD;  // (B,L,D)

    float* ws   = (float*)d_ws;
    float* qkv  = ws;                          // 3*BLD (featurized q_f|k_f|v)
    float* xn   = ws + (size_t)3 * BLD;        // BLD; reused as attn
    float* attn = xn;
    float* wtq  = ws + (size_t)4 * BLD;        // 1,769,472 (Wt_qkv)
    float* cbuf = wtq;                         // alias: wtq dead after qkv GEMM
    float* wts  = wtq + (size_t)Dc * 3 * Dc;   // 589,824 (Wt_gate, then Wt_proj)

    // 1) LayerNorm
    ln_kernel<<<Mrows, 256, 0, stream>>>(x, ln_g, ln_b, xn);
    // 2) gate = sigmoid(x @ W_gate + b_gate)
    transpose_kernel<<<dim3(Dc / 32, Dc / 32), 256, 0, stream>>>(W_gate, wts, Dc, Dc);
    gemm_mfma<1, 3><<<dim3(Dc / 128, Mrows / 128), 256, 0, stream>>>(
        x, wts, b_gate, nullptr, out_gate, Mrows, Dc, Dc);
    // 3) qkv = xn @ W_qkv + b_qkv, featurized epilogue
    transpose_kernel<<<dim3(3 * Dc / 32, Dc / 32), 256, 0, stream>>>(W_qkv, wtq, Dc, 3 * Dc);
    gemm_mfma<2, 3><<<dim3(3 * Dc / 128, Mrows / 128), 256, 0, stream>>>(
        xn, wtq, b_qkv, out_gate, qkv, Mrows, 3 * Dc, Dc);
    // 4-6) chunked causal linear attention
    chunk_sum2<<<dim3(NC, Bc * Hc), 64, 0, stream>>>(qkv, cbuf);
    scan_kernel<<<dim3(17, Bc * Hc), 256, 0, stream>>>(cbuf);
    chunk_out2<<<dim3(NC, Bc * Hc), 64, 0, stream>>>(qkv, cbuf, attn);
    // 7) out = attn @ W_proj + b_proj
    transpose_kernel<<<dim3(Dc / 32, Dc / 32), 256, 0, stream>>>(W_proj, wts, Dc, Dc);
    gemm_mfma<0, 3><<<dim3(Dc / 128, Mrows / 128), 256, 0, stream>>>(
        attn, wts, b_proj, nullptr, out_proj, Mrows, Dc, Dc);
}

// Round 4
// 307.983 us; speedup vs baseline: 1.2694x; 1.2694x over previous
//
#include <hip/hip_runtime.h>
#include <hip/hip_bf16.h>
#include <math.h>

#define Bc 2
#define Lc 1024
#define Dc 768
#define Hc 12
#define DHc 64
#define BLD (Bc * Lc * Dc)   // 1,572,864
#define Mrows (Bc * Lc)      // 2048
#define CS 64
#define NC (Lc / CS)         // 16
#define STATE (DHc * DHc + DHc)  // 4160

using f32x4  = __attribute__((ext_vector_type(4))) float;
using bf16x8 = __attribute__((ext_vector_type(8))) short;
using bf16x4 = __attribute__((ext_vector_type(4))) short;

__device__ inline short f2bf(float x) {  // RNE fp32 -> bf16 bits
    unsigned u = __builtin_bit_cast(unsigned, x);
    u = (u + 0x7FFFu + ((u >> 16) & 1u)) >> 16;
    return (short)u;
}
__device__ inline float bf2f(short s) {
    unsigned u = ((unsigned)(unsigned short)s) << 16;
    return __builtin_bit_cast(float, u);
}

// ---------------------------------------------------------------------------
// LayerNorm (unchanged)
// ---------------------------------------------------------------------------
__global__ __launch_bounds__(256) void ln_kernel(const float* __restrict__ x,
                                                 const float* __restrict__ g,
                                                 const float* __restrict__ b,
                                                 float* __restrict__ xn) {
    const int row = blockIdx.x;
    const float* xr = x + (size_t)row * Dc;
    float v[3];
    float s = 0.f, ss = 0.f;
#pragma unroll
    for (int i = 0; i < 3; ++i) {
        v[i] = xr[threadIdx.x + i * 256];
        s += v[i];
        ss += v[i] * v[i];
    }
#pragma unroll
    for (int off = 32; off > 0; off >>= 1) {
        s  += __shfl_down(s, off, 64);
        ss += __shfl_down(ss, off, 64);
    }
    __shared__ float sw[2][4];
    const int wave = threadIdx.x >> 6;
    const int lane = threadIdx.x & 63;
    if (lane == 0) { sw[0][wave] = s; sw[1][wave] = ss; }
    __syncthreads();
    s  = sw[0][0] + sw[0][1] + sw[0][2] + sw[0][3];
    ss = sw[1][0] + sw[1][1] + sw[1][2] + sw[1][3];
    const float mu = s * (1.f / Dc);
    const float var = ss * (1.f / Dc) - mu * mu;
    const float rstd = rsqrtf(var + 1e-5f);
    float* xo = xn + (size_t)row * Dc;
#pragma unroll
    for (int i = 0; i < 3; ++i) {
        const int c = threadIdx.x + i * 256;
        xo[c] = (v[i] - mu) * rstd * g[c] + b[c];
    }
}

// ---------------------------------------------------------------------------
// Weight transpose: W (K x N) -> Wt (N x K), 32x32 LDS tiles
// ---------------------------------------------------------------------------
__global__ __launch_bounds__(256) void transpose_kernel(const float* __restrict__ W,
                                                        float* __restrict__ Wt,
                                                        int K, int N) {
    __shared__ float t[32][33];
    const int bx = blockIdx.x * 32;  // n
    const int by = blockIdx.y * 32;  // k
    const int tx = threadIdx.x & 31, ty = threadIdx.x >> 5;  // ty 0..7
#pragma unroll
    for (int j = 0; j < 4; ++j)
        t[ty + 8 * j][tx] = W[(size_t)(by + ty + 8 * j) * N + bx + tx];
    __syncthreads();
#pragma unroll
    for (int j = 0; j < 4; ++j)
        Wt[(size_t)(bx + ty + 8 * j) * K + by + tx] = t[tx][ty + 8 * j];
}

// ---------------------------------------------------------------------------
// bf16x2-split MFMA GEMM (unchanged from round 3 — passed, absmax-neutral)
// ---------------------------------------------------------------------------
template <int EPI, int NP>
__global__ __launch_bounds__(256) void gemm_mfma(const float* __restrict__ A,
                                                 const float* __restrict__ Bt,
                                                 const float* __restrict__ bias,
                                                 const float* __restrict__ gate,
                                                 float* __restrict__ C,
                                                 int M, int N, int K) {
    __shared__ short Ah[128][40];
    __shared__ short Bh[128][40];
    __shared__ short Al[128][40];
    __shared__ short Bl[128][40];
    const int tid  = threadIdx.x;
    const int lane = tid & 63;
    const int wave = tid >> 6;
    const int wr = (wave >> 1) * 64;
    const int wc = (wave & 1) * 64;
    const int l15 = lane & 15;
    const int l4  = lane >> 4;
    const int row0 = blockIdx.y * 128;
    const int col0 = blockIdx.x * 128;

    f32x4 acc[4][4];
    const f32x4 zero = {0.f, 0.f, 0.f, 0.f};
#pragma unroll
    for (int i = 0; i < 4; ++i)
#pragma unroll
        for (int j = 0; j < 4; ++j) acc[i][j] = zero;

    for (int k0 = 0; k0 < K; k0 += 32) {
#pragma unroll
        for (int j = 0; j < 4; ++j) {
            const int i  = tid + j * 256;       // 0..1023
            const int r  = i >> 3;              // 0..127
            const int c4 = (i & 7) * 4;         // 0..28
            const float4 av = *reinterpret_cast<const float4*>(
                &A[(size_t)(row0 + r) * K + k0 + c4]);
            const float4 bv = *reinterpret_cast<const float4*>(
                &Bt[(size_t)(col0 + r) * K + k0 + c4]);
            const float aa[4] = {av.x, av.y, av.z, av.w};
            const float bb[4] = {bv.x, bv.y, bv.z, bv.w};
            bf16x4 ah, bh, al, bl;
#pragma unroll
            for (int e = 0; e < 4; ++e) {
                const short h = f2bf(aa[e]); ah[e] = h;
                const short g = f2bf(bb[e]); bh[e] = g;
                if (NP > 1) {
                    al[e] = f2bf(aa[e] - bf2f(h));
                    bl[e] = f2bf(bb[e] - bf2f(g));
                }
            }
            *reinterpret_cast<bf16x4*>(&Ah[r][c4]) = ah;
            *reinterpret_cast<bf16x4*>(&Bh[r][c4]) = bh;
            if (NP > 1) {
                *reinterpret_cast<bf16x4*>(&Al[r][c4]) = al;
                *reinterpret_cast<bf16x4*>(&Bl[r][c4]) = bl;
            }
        }
        __syncthreads();
        bf16x8 af[4], bfr[4], afl[4], bfl[4];
#pragma unroll
        for (int f = 0; f < 4; ++f) {
            af[f]  = *reinterpret_cast<bf16x8*>(&Ah[wr + f * 16 + l15][l4 * 8]);
            bfr[f] = *reinterpret_cast<bf16x8*>(&Bh[wc + f * 16 + l15][l4 * 8]);
            if (NP > 1) {
                afl[f] = *reinterpret_cast<bf16x8*>(&Al[wr + f * 16 + l15][l4 * 8]);
                bfl[f] = *reinterpret_cast<bf16x8*>(&Bl[wc + f * 16 + l15][l4 * 8]);
            }
        }
#pragma unroll
        for (int fi = 0; fi < 4; ++fi)
#pragma unroll
            for (int fj = 0; fj < 4; ++fj) {
                acc[fi][fj] = __builtin_amdgcn_mfma_f32_16x16x32_bf16(
                    af[fi], bfr[fj], acc[fi][fj], 0, 0, 0);
                if (NP > 1) {
                    acc[fi][fj] = __builtin_amdgcn_mfma_f32_16x16x32_bf16(
                        afl[fi], bfr[fj], acc[fi][fj], 0, 0, 0);
                    acc[fi][fj] = __builtin_amdgcn_mfma_f32_16x16x32_bf16(
                        af[fi], bfl[fj], acc[fi][fj], 0, 0, 0);
                }
            }
        __syncthreads();
    }
#pragma unroll
    for (int fi = 0; fi < 4; ++fi) {
#pragma unroll
        for (int fj = 0; fj < 4; ++fj) {
            const int col  = col0 + wc + fj * 16 + l15;
            const int rowb = row0 + wr + fi * 16 + l4 * 4;
            const float bv = bias[col];
#pragma unroll
            for (int j = 0; j < 4; ++j) {
                float v = acc[fi][fj][j] + bv;
                const int r = rowb + j;
                if (EPI == 1) v = 1.f / (1.f + expf(-v));
                if (EPI == 2) {
                    if (col < 2 * Dc) {
                        float t = v;
                        if (col >= Dc) t *= gate[(size_t)r * Dc + (col - Dc)];
                        v = t > 0.f ? t + 1.f : expf(t);
                    }
                }
                C[(size_t)r * N + col] = v;
            }
        }
    }
}

// ---------------------------------------------------------------------------
// Phase A: chunk-local KV state = K_c^T @ V_c (64x64) and ksum.
// 256 threads; thread (g4=tid>>6, e=tid&63) owns rows d0..d0+15, col e.
// K staged in LDS (broadcast reuse); V read coalesced from global (used once).
// ---------------------------------------------------------------------------
__global__ __launch_bounds__(256) void chunk_kv(const float* __restrict__ qkv,
                                                float* __restrict__ cbuf) {
    const int c = blockIdx.x, bh = blockIdx.y;
    const int b = bh / Hc, h = bh % Hc;
    const int tid = threadIdx.x;
    const int e  = tid & 63;
    const int g4 = tid >> 6;
    const int d0 = g4 * 16;

    __shared__ float Ks[CS][DHc];  // [l][d]; reads are wave-uniform b128 or stride-1

    const size_t row0  = (size_t)b * Lc + c * CS;
    const size_t qbase = row0 * (3 * Dc) + h * DHc;
#pragma unroll
    for (int j = 0; j < 4; ++j) {
        const int fi = tid + j * 256;        // 0..1023
        const int r  = fi >> 4;              // 0..63
        const int c4 = (fi & 15) * 4;        // 0..60
        *reinterpret_cast<float4*>(&Ks[r][c4]) =
            *reinterpret_cast<const float4*>(&qkv[qbase + (size_t)r * 3 * Dc + Dc + c4]);
    }
    __syncthreads();

    float S[16];
#pragma unroll
    for (int i = 0; i < 16; ++i) S[i] = 0.f;
    float ksum = 0.f;
    for (int l = 0; l < CS; ++l) {
        const float vv = qkv[qbase + (size_t)l * 3 * Dc + 2 * Dc + e];  // coalesced
        if (g4 == 0) ksum += Ks[l][e];  // stride-1, conflict-free
#pragma unroll
        for (int i4 = 0; i4 < 4; ++i4) {
            const float4 k4 = *reinterpret_cast<const float4*>(&Ks[l][d0 + i4 * 4]);
            S[i4 * 4 + 0] = fmaf(k4.x, vv, S[i4 * 4 + 0]);
            S[i4 * 4 + 1] = fmaf(k4.y, vv, S[i4 * 4 + 1]);
            S[i4 * 4 + 2] = fmaf(k4.z, vv, S[i4 * 4 + 2]);
            S[i4 * 4 + 3] = fmaf(k4.w, vv, S[i4 * 4 + 3]);
        }
    }
    float* out = cbuf + ((size_t)bh * NC + c) * STATE;
#pragma unroll
    for (int i = 0; i < 16; ++i) out[(d0 + i) * DHc + e] = S[i];
    if (g4 == 0) out[DHc * DHc + e] = ksum;
}

// ---------------------------------------------------------------------------
// Phase B: exclusive prefix scan over NC chunk states
// ---------------------------------------------------------------------------
__global__ __launch_bounds__(256) void scan_kernel(float* __restrict__ cbuf) {
    const int idx = blockIdx.x * 256 + threadIdx.x;
    if (idx >= STATE) return;
    float* base = cbuf + (size_t)blockIdx.y * NC * STATE + idx;
    float r = 0.f;
    for (int c = 0; c < NC; ++c) {
        const float cur = base[(size_t)c * STATE];
        base[(size_t)c * STATE] = r;
        r += cur;
    }
}

// ---------------------------------------------------------------------------
// Phase C (matrix form, no recurrence):
//   Sqk = tril(Q_c @ K_c^T)           (64x64)
//   num = Q_c @ P + Sqk @ V_c         (64x64)
//   den = rowsum(Sqk) + Q_c @ kcP     (64)
//   attn = num / (den + 1e-6)
// 256 threads; thread (g4,e) computes rows l0..l0+15 at column e.
// ---------------------------------------------------------------------------
__global__ __launch_bounds__(256) void chunk_qkv_out(const float* __restrict__ qkv,
                                                     const float* __restrict__ cbuf,
                                                     float* __restrict__ attn) {
    const int c = blockIdx.x, bh = blockIdx.y;
    const int b = bh / Hc, h = bh % Hc;
    const int tid = threadIdx.x;
    const int e  = tid & 63;
    const int g4 = tid >> 6;
    const int l0 = g4 * 16;

    __shared__ float Qs[64][68];  // pad 68: b128-aligned rows, broadcast reads
    __shared__ float Kt[64][65];  // transposed: Kt[d][e]; stride-1 lane reads
    __shared__ float Ss[64][68];  // Sqk (masked)
    __shared__ float dq[64];      // Q @ kcP

    const size_t row0  = (size_t)b * Lc + c * CS;
    const size_t qbase = row0 * (3 * Dc) + h * DHc;

    // stage Q rows + K transposed
#pragma unroll
    for (int j = 0; j < 4; ++j) {
        const int fi = tid + j * 256;
        const int r  = fi >> 4;
        const int c4 = (fi & 15) * 4;
        const float4 q4 = *reinterpret_cast<const float4*>(
            &qkv[qbase + (size_t)r * 3 * Dc + c4]);
        *reinterpret_cast<float4*>(&Qs[r][c4]) = q4;
        const float4 k4 = *reinterpret_cast<const float4*>(
            &qkv[qbase + (size_t)r * 3 * Dc + Dc + c4]);
        Kt[c4 + 0][r] = k4.x;
        Kt[c4 + 1][r] = k4.y;
        Kt[c4 + 2][r] = k4.z;
        Kt[c4 + 3][r] = k4.w;
    }
    __syncthreads();

    const float* Pp  = cbuf + ((size_t)bh * NC + c) * STATE;
    const float* kcP = Pp + DHc * DHc;

    // Phase 1: Sqk[l][e] for l = l0..l0+15
    float acc[16];
#pragma unroll
    for (int i = 0; i < 16; ++i) acc[i] = 0.f;
#pragma unroll 4
    for (int d4 = 0; d4 < 16; ++d4) {
        const float k0 = Kt[d4 * 4 + 0][e];
        const float k1 = Kt[d4 * 4 + 1][e];
        const float k2 = Kt[d4 * 4 + 2][e];
        const float k3 = Kt[d4 * 4 + 3][e];
#pragma unroll
        for (int i = 0; i < 16; ++i) {
            const float4 q4 = *reinterpret_cast<const float4*>(&Qs[l0 + i][d4 * 4]);
            acc[i] = fmaf(q4.x, k0, acc[i]);
            acc[i] = fmaf(q4.y, k1, acc[i]);
            acc[i] = fmaf(q4.z, k2, acc[i]);
            acc[i] = fmaf(q4.w, k3, acc[i]);
        }
    }
    // mask, rowsum butterfly, store
    float den[16];
#pragma unroll
    for (int i = 0; i < 16; ++i) {
        const float m = (e <= l0 + i) ? acc[i] : 0.f;
        Ss[l0 + i][e] = m;
        float r = m;
#pragma unroll
        for (int off = 32; off > 0; off >>= 1) r += __shfl_xor(r, off, 64);
        den[i] = r;
    }
    // wave 0: dq[l] = Q[l] . kcP
    if (g4 == 0) {
        float s = 0.f;
#pragma unroll 8
        for (int d = 0; d < 64; ++d) s = fmaf(Qs[e][d], kcP[d], s);
        dq[e] = s;
    }
    __syncthreads();

    // Phase 2: num = Q@P + Ss@V
    float num[16];
#pragma unroll
    for (int i = 0; i < 16; ++i) num[i] = 0.f;
#pragma unroll 4
    for (int d4 = 0; d4 < 16; ++d4) {
        const float p0 = Pp[(d4 * 4 + 0) * DHc + e];  // coalesced global
        const float p1 = Pp[(d4 * 4 + 1) * DHc + e];
        const float p2 = Pp[(d4 * 4 + 2) * DHc + e];
        const float p3 = Pp[(d4 * 4 + 3) * DHc + e];
#pragma unroll
        for (int i = 0; i < 16; ++i) {
            const float4 q4 = *reinterpret_cast<const float4*>(&Qs[l0 + i][d4 * 4]);
            num[i] = fmaf(q4.x, p0, num[i]);
            num[i] = fmaf(q4.y, p1, num[i]);
            num[i] = fmaf(q4.z, p2, num[i]);
            num[i] = fmaf(q4.w, p3, num[i]);
        }
    }
#pragma unroll 4
    for (int j4 = 0; j4 < 16; ++j4) {
        const float v0 = qkv[qbase + (size_t)(j4 * 4 + 0) * 3 * Dc + 2 * Dc + e];
        const float v1 = qkv[qbase + (size_t)(j4 * 4 + 1) * 3 * Dc + 2 * Dc + e];
        const float v2 = qkv[qbase + (size_t)(j4 * 4 + 2) * 3 * Dc + 2 * Dc + e];
        const float v3 = qkv[qbase + (size_t)(j4 * 4 + 3) * 3 * Dc + 2 * Dc + e];
#pragma unroll
        for (int i = 0; i < 16; ++i) {
            const float4 s4 = *reinterpret_cast<const float4*>(&Ss[l0 + i][j4 * 4]);
            num[i] = fmaf(s4.x, v0, num[i]);
            num[i] = fmaf(s4.y, v1, num[i]);
            num[i] = fmaf(s4.z, v2, num[i]);
            num[i] = fmaf(s4.w, v3, num[i]);
        }
    }
#pragma unroll
    for (int i = 0; i < 16; ++i) {
        const float dd = den[i] + dq[l0 + i] + 1e-6f;
        attn[(row0 + l0 + i) * Dc + h * DHc + e] = num[i] / dd;
    }
}

// ---------------------------------------------------------------------------
extern "C" void kernel_launch(void* const* d_in, const int* in_sizes, int n_in,
                              void* d_out, int out_size, void* d_ws, size_t ws_size,
                              hipStream_t stream) {
    const float* x      = (const float*)d_in[0];
    const float* W_qkv  = (const float*)d_in[1];
    const float* b_qkv  = (const float*)d_in[2];
    const float* W_gate = (const float*)d_in[3];
    const float* b_gate = (const float*)d_in[4];
    const float* W_proj = (const float*)d_in[5];
    const float* b_proj = (const float*)d_in[6];
    const float* ln_g   = (const float*)d_in[7];
    const float* ln_b   = (const float*)d_in[8];

    float* out_proj = (float*)d_out;           // (B,L,D)
    float* out_gate = out_proj + (size_t)BLD;  // (B,L,D)

    float* ws   = (float*)d_ws;
    float* qkv  = ws;                          // 3*BLD (featurized q_f|k_f|v)
    float* xn   = ws + (size_t)3 * BLD;        // BLD; reused as attn
    float* attn = xn;
    float* wtq  = ws + (size_t)4 * BLD;        // Wt_qkv (dead after qkv GEMM)
    float* cbuf = wtq;                         // alias
    float* wts  = wtq + (size_t)Dc * 3 * Dc;   // Wt_gate, then Wt_proj

    ln_kernel<<<Mrows, 256, 0, stream>>>(x, ln_g, ln_b, xn);
    transpose_kernel<<<dim3(Dc / 32, Dc / 32), 256, 0, stream>>>(W_gate, wts, Dc, Dc);
    gemm_mfma<1, 3><<<dim3(Dc / 128, Mrows / 128), 256, 0, stream>>>(
        x, wts, b_gate, nullptr, out_gate, Mrows, Dc, Dc);
    transpose_kernel<<<dim3(3 * Dc / 32, Dc / 32), 256, 0, stream>>>(W_qkv, wtq, Dc, 3 * Dc);
    gemm_mfma<2, 3><<<dim3(3 * Dc / 128, Mrows / 128), 256, 0, stream>>>(
        xn, wtq, b_qkv, out_gate, qkv, Mrows, 3 * Dc, Dc);
    chunk_kv<<<dim3(NC, Bc * Hc), 256, 0, stream>>>(qkv, cbuf);
    scan_kernel<<<dim3(17, Bc * Hc), 256, 0, stream>>>(cbuf);
    chunk_qkv_out<<<dim3(NC, Bc * Hc), 256, 0, stream>>>(qkv, cbuf, attn);
    transpose_kernel<<<dim3(Dc / 32, Dc / 32), 256, 0, stream>>>(W_proj, wts, Dc, Dc);
    gemm_mfma<0, 3><<<dim3(Dc / 128, Mrows / 128), 256, 0, stream>>>(
        attn, wts, b_proj, nullptr, out_proj, Mrows, Dc, Dc);
}

// Round 5
// 249.405 us; speedup vs baseline: 1.5675x; 1.2349x over previous
//
#include <hip/hip_runtime.h>
#include <hip/hip_bf16.h>
#include <math.h>

#define Bc 2
#define Lc 1024
#define Dc 768
#define Hc 12
#define DHc 64
#define BLD (Bc * Lc * Dc)   // 1,572,864
#define Mrows (Bc * Lc)      // 2048
#define CS 64
#define NC (Lc / CS)         // 16
#define STATE (DHc * DHc + DHc)  // 4160

using f32x4  = __attribute__((ext_vector_type(4))) float;
using bf16x8 = __attribute__((ext_vector_type(8))) short;
typedef unsigned int u32;

__device__ inline short f2bf(float x) {  // RNE fp32 -> bf16 bits
    unsigned u = __builtin_bit_cast(unsigned, x);
    u = (u + 0x7FFFu + ((u >> 16) & 1u)) >> 16;
    return (short)u;
}
__device__ inline float bf2f(short s) {
    unsigned u = ((unsigned)(unsigned short)s) << 16;
    return __builtin_bit_cast(float, u);
}
__device__ __forceinline__ void gll16(const short* g, short* l) {
    __builtin_amdgcn_global_load_lds(
        (const __attribute__((address_space(1))) u32*)g,
        (__attribute__((address_space(3))) u32*)l, 16, 0, 0);
}

// ---------------------------------------------------------------------------
// LayerNorm + emit bf16 hi/lo splits of BOTH raw x and normalized xn
// ---------------------------------------------------------------------------
__global__ __launch_bounds__(256) void ln_kernel(const float* __restrict__ x,
                                                 const float* __restrict__ g,
                                                 const float* __restrict__ b,
                                                 short* __restrict__ xh,
                                                 short* __restrict__ xl,
                                                 short* __restrict__ xnh,
                                                 short* __restrict__ xnl) {
    const int row = blockIdx.x;
    const float* xr = x + (size_t)row * Dc;
    float v[3];
    float s = 0.f, ss = 0.f;
#pragma unroll
    for (int i = 0; i < 3; ++i) {
        v[i] = xr[threadIdx.x + i * 256];
        s += v[i];
        ss += v[i] * v[i];
    }
#pragma unroll
    for (int off = 32; off > 0; off >>= 1) {
        s  += __shfl_down(s, off, 64);
        ss += __shfl_down(ss, off, 64);
    }
    __shared__ float sw[2][4];
    const int wave = threadIdx.x >> 6;
    const int lane = threadIdx.x & 63;
    if (lane == 0) { sw[0][wave] = s; sw[1][wave] = ss; }
    __syncthreads();
    s  = sw[0][0] + sw[0][1] + sw[0][2] + sw[0][3];
    ss = sw[1][0] + sw[1][1] + sw[1][2] + sw[1][3];
    const float mu = s * (1.f / Dc);
    const float var = ss * (1.f / Dc) - mu * mu;
    const float rstd = rsqrtf(var + 1e-5f);
    const size_t base = (size_t)row * Dc;
#pragma unroll
    for (int i = 0; i < 3; ++i) {
        const int c = threadIdx.x + i * 256;
        const float xv = v[i];
        short hh = f2bf(xv);
        xh[base + c] = hh;
        xl[base + c] = f2bf(xv - bf2f(hh));
        const float xnv = (xv - mu) * rstd * g[c] + b[c];
        hh = f2bf(xnv);
        xnh[base + c] = hh;
        xnl[base + c] = f2bf(xnv - bf2f(hh));
    }
}

// ---------------------------------------------------------------------------
// Weight transpose + split: W (K x N) fp32 -> Wh, Wl (N x K) bf16
// ---------------------------------------------------------------------------
__global__ __launch_bounds__(256) void transpose_split(const float* __restrict__ W,
                                                       short* __restrict__ Wh,
                                                       short* __restrict__ Wl,
                                                       int K, int N) {
    __shared__ float t[32][33];
    const int bx = blockIdx.x * 32;  // n
    const int by = blockIdx.y * 32;  // k
    const int tx = threadIdx.x & 31, ty = threadIdx.x >> 5;  // ty 0..7
#pragma unroll
    for (int j = 0; j < 4; ++j)
        t[ty + 8 * j][tx] = W[(size_t)(by + ty + 8 * j) * N + bx + tx];
    __syncthreads();
#pragma unroll
    for (int j = 0; j < 4; ++j) {
        const float v = t[tx][ty + 8 * j];
        const short hh = f2bf(v);
        const size_t o = (size_t)(bx + ty + 8 * j) * K + by + tx;
        Wh[o] = hh;
        Wl[o] = f2bf(v - bf2f(hh));
    }
}

// ---------------------------------------------------------------------------
// Pure-bf16 MFMA GEMM over virtual K' = 3*768 (hi*hi + lo*hi + hi*lo).
// C[M,64N-blocks] = A @ B^T + bias. A*, B* are (rows x 768) bf16 row-major.
// 64x64 tile, 4 waves (2x2 of 32x32), BK=64, double-buffered global_load_lds,
// XOR chunk-swizzle (phys = logical ^ (row&7)) on source + ds_read.
// EPI: 0 none, 1 sigmoid, 2 qkv featurize.
// ---------------------------------------------------------------------------
template <int EPI>
__global__ __launch_bounds__(256) void gemm_bf16(const short* __restrict__ Ah,
                                                 const short* __restrict__ Al,
                                                 const short* __restrict__ Bh,
                                                 const short* __restrict__ Bl,
                                                 const float* __restrict__ bias,
                                                 const float* __restrict__ gate,
                                                 float* __restrict__ C, int N) {
    __shared__ short Alds[2][64 * 64];
    __shared__ short Blds[2][64 * 64];
    const int tid  = threadIdx.x;
    const int lane = tid & 63;
    const int wv  = tid >> 6;
    const int wr  = (wv >> 1) * 32;
    const int wc  = (wv & 1) * 32;
    const int l15 = lane & 15;
    const int l4  = lane >> 4;
    const int r8  = lane >> 3;   // 0..7
    const int ch  = lane & 7;    // 0..7
    const int sChunk = ((ch ^ r8) * 8);  // pre-swizzled source element offset
    const int row0 = blockIdx.y * 64;
    const int col0 = blockIdx.x * 64;

    f32x4 acc[2][2];
    const f32x4 zero = {0.f, 0.f, 0.f, 0.f};
#pragma unroll
    for (int i = 0; i < 2; ++i)
#pragma unroll
        for (int j = 0; j < 2; ++j) acc[i][j] = zero;

    auto STAGE = [&](int buf, int s) {
        const int seg = s / 12, t = s - seg * 12;
        const short* ap = (seg == 1 ? Al : Ah) + t * 64;
        const short* bp = (seg == 2 ? Bl : Bh) + t * 64;
        const short* as = ap + (size_t)(row0 + 16 * wv + r8) * 768 + sChunk;
        gll16(as,           &Alds[buf][(16 * wv) * 64]);
        gll16(as + 8 * 768, &Alds[buf][(16 * wv + 8) * 64]);
        const short* bs = bp + (size_t)(col0 + 16 * wv + r8) * 768 + sChunk;
        gll16(bs,           &Blds[buf][(16 * wv) * 64]);
        gll16(bs + 8 * 768, &Blds[buf][(16 * wv + 8) * 64]);
    };

    STAGE(0, 0);
    asm volatile("s_waitcnt vmcnt(0)" ::: "memory");
    __builtin_amdgcn_s_barrier();

    const int pa0 = ((l4)     ^ (l15 & 7)) * 8;  // ksub 0 phys chunk
    const int pa1 = ((4 + l4) ^ (l15 & 7)) * 8;  // ksub 1 phys chunk
    int buf = 0;
    for (int s = 0; s < 36; ++s) {
        if (s + 1 < 36) STAGE(buf ^ 1, s + 1);
        const short* AB = Alds[buf];
        const short* BB = Blds[buf];
        const bf16x8 a00 = *(const bf16x8*)&AB[(wr + l15) * 64 + pa0];
        const bf16x8 a10 = *(const bf16x8*)&AB[(wr + 16 + l15) * 64 + pa0];
        const bf16x8 b00 = *(const bf16x8*)&BB[(wc + l15) * 64 + pa0];
        const bf16x8 b10 = *(const bf16x8*)&BB[(wc + 16 + l15) * 64 + pa0];
        const bf16x8 a01 = *(const bf16x8*)&AB[(wr + l15) * 64 + pa1];
        const bf16x8 a11 = *(const bf16x8*)&AB[(wr + 16 + l15) * 64 + pa1];
        const bf16x8 b01 = *(const bf16x8*)&BB[(wc + l15) * 64 + pa1];
        const bf16x8 b11 = *(const bf16x8*)&BB[(wc + 16 + l15) * 64 + pa1];
        acc[0][0] = __builtin_amdgcn_mfma_f32_16x16x32_bf16(a00, b00, acc[0][0], 0, 0, 0);
        acc[0][1] = __builtin_amdgcn_mfma_f32_16x16x32_bf16(a00, b10, acc[0][1], 0, 0, 0);
        acc[1][0] = __builtin_amdgcn_mfma_f32_16x16x32_bf16(a10, b00, acc[1][0], 0, 0, 0);
        acc[1][1] = __builtin_amdgcn_mfma_f32_16x16x32_bf16(a10, b10, acc[1][1], 0, 0, 0);
        acc[0][0] = __builtin_amdgcn_mfma_f32_16x16x32_bf16(a01, b01, acc[0][0], 0, 0, 0);
        acc[0][1] = __builtin_amdgcn_mfma_f32_16x16x32_bf16(a01, b11, acc[0][1], 0, 0, 0);
        acc[1][0] = __builtin_amdgcn_mfma_f32_16x16x32_bf16(a11, b01, acc[1][0], 0, 0, 0);
        acc[1][1] = __builtin_amdgcn_mfma_f32_16x16x32_bf16(a11, b11, acc[1][1], 0, 0, 0);
        asm volatile("s_waitcnt vmcnt(0)" ::: "memory");
        __builtin_amdgcn_s_barrier();
        buf ^= 1;
    }

    // epilogue: C/D mapping col=lane&15, row=(lane>>4)*4+reg
#pragma unroll
    for (int fi = 0; fi < 2; ++fi) {
#pragma unroll
        for (int fj = 0; fj < 2; ++fj) {
            const int col  = col0 + wc + fj * 16 + l15;
            const int rowb = row0 + wr + fi * 16 + l4 * 4;
            const float bv = bias[col];
#pragma unroll
            for (int j = 0; j < 4; ++j) {
                float v = acc[fi][fj][j] + bv;
                const int r = rowb + j;
                if (EPI == 1) v = 1.f / (1.f + expf(-v));
                if (EPI == 2) {
                    if (col < 2 * Dc) {
                        float t = v;
                        if (col >= Dc) t *= gate[(size_t)r * Dc + (col - Dc)];
                        v = t > 0.f ? t + 1.f : expf(t);
                    }
                }
                C[(size_t)r * N + col] = v;
            }
        }
    }
}

// ---------------------------------------------------------------------------
// Phase A: chunk-local KV state = K_c^T @ V_c (64x64) and ksum (unchanged)
// ---------------------------------------------------------------------------
__global__ __launch_bounds__(256) void chunk_kv(const float* __restrict__ qkv,
                                                float* __restrict__ cbuf) {
    const int c = blockIdx.x, bh = blockIdx.y;
    const int b = bh / Hc, h = bh % Hc;
    const int tid = threadIdx.x;
    const int e  = tid & 63;
    const int g4 = tid >> 6;
    const int d0 = g4 * 16;

    __shared__ float Ks[CS][DHc];

    const size_t row0  = (size_t)b * Lc + c * CS;
    const size_t qbase = row0 * (3 * Dc) + h * DHc;
#pragma unroll
    for (int j = 0; j < 4; ++j) {
        const int fi = tid + j * 256;
        const int r  = fi >> 4;
        const int c4 = (fi & 15) * 4;
        *reinterpret_cast<float4*>(&Ks[r][c4]) =
            *reinterpret_cast<const float4*>(&qkv[qbase + (size_t)r * 3 * Dc + Dc + c4]);
    }
    __syncthreads();

    float S[16];
#pragma unroll
    for (int i = 0; i < 16; ++i) S[i] = 0.f;
    float ksum = 0.f;
    for (int l = 0; l < CS; ++l) {
        const float vv = qkv[qbase + (size_t)l * 3 * Dc + 2 * Dc + e];
        if (g4 == 0) ksum += Ks[l][e];
#pragma unroll
        for (int i4 = 0; i4 < 4; ++i4) {
            const float4 k4 = *reinterpret_cast<const float4*>(&Ks[l][d0 + i4 * 4]);
            S[i4 * 4 + 0] = fmaf(k4.x, vv, S[i4 * 4 + 0]);
            S[i4 * 4 + 1] = fmaf(k4.y, vv, S[i4 * 4 + 1]);
            S[i4 * 4 + 2] = fmaf(k4.z, vv, S[i4 * 4 + 2]);
            S[i4 * 4 + 3] = fmaf(k4.w, vv, S[i4 * 4 + 3]);
        }
    }
    float* out = cbuf + ((size_t)bh * NC + c) * STATE;
#pragma unroll
    for (int i = 0; i < 16; ++i) out[(d0 + i) * DHc + e] = S[i];
    if (g4 == 0) out[DHc * DHc + e] = ksum;
}

// ---------------------------------------------------------------------------
// Phase B: exclusive prefix scan over NC chunk states (unchanged)
// ---------------------------------------------------------------------------
__global__ __launch_bounds__(256) void scan_kernel(float* __restrict__ cbuf) {
    const int idx = blockIdx.x * 256 + threadIdx.x;
    if (idx >= STATE) return;
    float* base = cbuf + (size_t)blockIdx.y * NC * STATE + idx;
    float r = 0.f;
    for (int c = 0; c < NC; ++c) {
        const float cur = base[(size_t)c * STATE];
        base[(size_t)c * STATE] = r;
        r += cur;
    }
}

// ---------------------------------------------------------------------------
// Phase C (matrix form) -> writes attn as bf16 hi/lo splits
// ---------------------------------------------------------------------------
__global__ __launch_bounds__(256) void chunk_qkv_out(const float* __restrict__ qkv,
                                                     const float* __restrict__ cbuf,
                                                     short* __restrict__ attnh,
                                                     short* __restrict__ attnl) {
    const int c = blockIdx.x, bh = blockIdx.y;
    const int b = bh / Hc, h = bh % Hc;
    const int tid = threadIdx.x;
    const int e  = tid & 63;
    const int g4 = tid >> 6;
    const int l0 = g4 * 16;

    __shared__ float Qs[64][68];
    __shared__ float Kt[64][65];
    __shared__ float Ss[64][68];
    __shared__ float dq[64];

    const size_t row0  = (size_t)b * Lc + c * CS;
    const size_t qbase = row0 * (3 * Dc) + h * DHc;

#pragma unroll
    for (int j = 0; j < 4; ++j) {
        const int fi = tid + j * 256;
        const int r  = fi >> 4;
        const int c4 = (fi & 15) * 4;
        const float4 q4 = *reinterpret_cast<const float4*>(
            &qkv[qbase + (size_t)r * 3 * Dc + c4]);
        *reinterpret_cast<float4*>(&Qs[r][c4]) = q4;
        const float4 k4 = *reinterpret_cast<const float4*>(
            &qkv[qbase + (size_t)r * 3 * Dc + Dc + c4]);
        Kt[c4 + 0][r] = k4.x;
        Kt[c4 + 1][r] = k4.y;
        Kt[c4 + 2][r] = k4.z;
        Kt[c4 + 3][r] = k4.w;
    }
    __syncthreads();

    const float* Pp  = cbuf + ((size_t)bh * NC + c) * STATE;
    const float* kcP = Pp + DHc * DHc;

    float acc[16];
#pragma unroll
    for (int i = 0; i < 16; ++i) acc[i] = 0.f;
#pragma unroll 4
    for (int d4 = 0; d4 < 16; ++d4) {
        const float k0 = Kt[d4 * 4 + 0][e];
        const float k1 = Kt[d4 * 4 + 1][e];
        const float k2 = Kt[d4 * 4 + 2][e];
        const float k3 = Kt[d4 * 4 + 3][e];
#pragma unroll
        for (int i = 0; i < 16; ++i) {
            const float4 q4 = *reinterpret_cast<const float4*>(&Qs[l0 + i][d4 * 4]);
            acc[i] = fmaf(q4.x, k0, acc[i]);
            acc[i] = fmaf(q4.y, k1, acc[i]);
            acc[i] = fmaf(q4.z, k2, acc[i]);
            acc[i] = fmaf(q4.w, k3, acc[i]);
        }
    }
    float den[16];
#pragma unroll
    for (int i = 0; i < 16; ++i) {
        const float m = (e <= l0 + i) ? acc[i] : 0.f;
        Ss[l0 + i][e] = m;
        float r = m;
#pragma unroll
        for (int off = 32; off > 0; off >>= 1) r += __shfl_xor(r, off, 64);
        den[i] = r;
    }
    if (g4 == 0) {
        float s = 0.f;
#pragma unroll 8
        for (int d = 0; d < 64; ++d) s = fmaf(Qs[e][d], kcP[d], s);
        dq[e] = s;
    }
    __syncthreads();

    float num[16];
#pragma unroll
    for (int i = 0; i < 16; ++i) num[i] = 0.f;
#pragma unroll 4
    for (int d4 = 0; d4 < 16; ++d4) {
        const float p0 = Pp[(d4 * 4 + 0) * DHc + e];
        const float p1 = Pp[(d4 * 4 + 1) * DHc + e];
        const float p2 = Pp[(d4 * 4 + 2) * DHc + e];
        const float p3 = Pp[(d4 * 4 + 3) * DHc + e];
#pragma unroll
        for (int i = 0; i < 16; ++i) {
            const float4 q4 = *reinterpret_cast<const float4*>(&Qs[l0 + i][d4 * 4]);
            num[i] = fmaf(q4.x, p0, num[i]);
            num[i] = fmaf(q4.y, p1, num[i]);
            num[i] = fmaf(q4.z, p2, num[i]);
            num[i] = fmaf(q4.w, p3, num[i]);
        }
    }
#pragma unroll 4
    for (int j4 = 0; j4 < 16; ++j4) {
        const float v0 = qkv[qbase + (size_t)(j4 * 4 + 0) * 3 * Dc + 2 * Dc + e];
        const float v1 = qkv[qbase + (size_t)(j4 * 4 + 1) * 3 * Dc + 2 * Dc + e];
        const float v2 = qkv[qbase + (size_t)(j4 * 4 + 2) * 3 * Dc + 2 * Dc + e];
        const float v3 = qkv[qbase + (size_t)(j4 * 4 + 3) * 3 * Dc + 2 * Dc + e];
#pragma unroll
        for (int i = 0; i < 16; ++i) {
            const float4 s4 = *reinterpret_cast<const float4*>(&Ss[l0 + i][j4 * 4]);
            num[i] = fmaf(s4.x, v0, num[i]);
            num[i] = fmaf(s4.y, v1, num[i]);
            num[i] = fmaf(s4.z, v2, num[i]);
            num[i] = fmaf(s4.w, v3, num[i]);
        }
    }
#pragma unroll
    for (int i = 0; i < 16; ++i) {
        const float dd = den[i] + dq[l0 + i] + 1e-6f;
        const float o = num[i] / dd;
        const size_t oidx = (row0 + l0 + i) * Dc + h * DHc + e;
        const short hh = f2bf(o);
        attnh[oidx] = hh;
        attnl[oidx] = f2bf(o - bf2f(hh));
    }
}

// ---------------------------------------------------------------------------
extern "C" void kernel_launch(void* const* d_in, const int* in_sizes, int n_in,
                              void* d_out, int out_size, void* d_ws, size_t ws_size,
                              hipStream_t stream) {
    const float* x      = (const float*)d_in[0];
    const float* W_qkv  = (const float*)d_in[1];
    const float* b_qkv  = (const float*)d_in[2];
    const float* W_gate = (const float*)d_in[3];
    const float* b_gate = (const float*)d_in[4];
    const float* W_proj = (const float*)d_in[5];
    const float* b_proj = (const float*)d_in[6];
    const float* ln_g   = (const float*)d_in[7];
    const float* ln_b   = (const float*)d_in[8];

    float* out_proj = (float*)d_out;           // (B,L,D)
    float* out_gate = out_proj + (size_t)BLD;  // (B,L,D)

    float* ws  = (float*)d_ws;
    float* qkv = ws;                                  // 3*BLD fp32 (featurized)
    short* xnh = (short*)(ws + (size_t)3 * BLD);      // BLD shorts each
    short* xnl = xnh + (size_t)BLD;
    short* xh  = xnl + (size_t)BLD;
    short* xl  = xh  + (size_t)BLD;
    float* cbuf = (float*)xnh;                        // alias: dead after qkv gemm
    short* wqh = (short*)(ws + (size_t)3 * BLD + 2 * BLD);  // 768*2304 shorts each
    short* wql = wqh + (size_t)Dc * 3 * Dc;
    short* attnh = wqh;                               // alias: dead after qkv gemm
    short* attnl = attnh + (size_t)BLD;
    short* wgh = wql + (size_t)Dc * 3 * Dc;           // 768*768 shorts each
    short* wgl = wgh + (size_t)Dc * Dc;

    // 1) LayerNorm + x/xn bf16 splits
    ln_kernel<<<Mrows, 256, 0, stream>>>(x, ln_g, ln_b, xh, xl, xnh, xnl);
    // 2) gate = sigmoid(x @ W_gate + b_gate)
    transpose_split<<<dim3(Dc / 32, Dc / 32), 256, 0, stream>>>(W_gate, wgh, wgl, Dc, Dc);
    gemm_bf16<1><<<dim3(Dc / 64, Mrows / 64), 256, 0, stream>>>(
        xh, xl, wgh, wgl, b_gate, nullptr, out_gate, Dc);
    // 3) qkv = xn @ W_qkv + b_qkv, featurized epilogue
    transpose_split<<<dim3(3 * Dc / 32, Dc / 32), 256, 0, stream>>>(W_qkv, wqh, wql, Dc, 3 * Dc);
    gemm_bf16<2><<<dim3(3 * Dc / 64, Mrows / 64), 256, 0, stream>>>(
        xnh, xnl, wqh, wql, b_qkv, out_gate, qkv, 3 * Dc);
    // 4-6) chunked causal linear attention
    chunk_kv<<<dim3(NC, Bc * Hc), 256, 0, stream>>>(qkv, cbuf);
    scan_kernel<<<dim3(17, Bc * Hc), 256, 0, stream>>>(cbuf);
    chunk_qkv_out<<<dim3(NC, Bc * Hc), 256, 0, stream>>>(qkv, cbuf, attnh, attnl);
    // 7) out = attn @ W_proj + b_proj
    transpose_split<<<dim3(Dc / 32, Dc / 32), 256, 0, stream>>>(W_proj, wgh, wgl, Dc, Dc);
    gemm_bf16<0><<<dim3(Dc / 64, Mrows / 64), 256, 0, stream>>>(
        attnh, attnl, wgh, wgl, b_proj, nullptr, out_proj, Dc);
}